// Round 10
// baseline (4644.038 us; speedup 1.0000x reference)
//
#include <hip/hip_runtime.h>
#include <hip/hip_bf16.h>

// ---------------------------------------------------------------------------
// StateSpaceLite on MI355X.
//   u = x@W_in^T + b_in            (bf16 MFMA GEMM -> d_out, in place)
//   scan over t: driven = tanh(u_t + s@W_state^T + b_state)
//                s' = d*s + (1-d)*driven ; y_t = LN(s')*gamma + beta
// Round-10: round-8 topology+protocol (proven: 64 blocks x 16 cols, MFMA over
// all 64 batch rows, W in LDS, agent-relaxed bf16 state + fp32 LN partials,
// flag barrier + one agent acquire fence per block/step). New:
//  (1) all 40 per-step loads issued as volatile-asm dwordx4 -> ONE vmcnt(0)
//      wait group (one IC round trip instead of 2-4),
//  (2) in-loop raw s_barrier with manual counted drain: only S/P store-acks
//      gate the flag; y_{t-1} stores + u_{t+1} loads issue in the poll window
//      and are absorbed by the next step's vmcnt(0).
// ---------------------------------------------------------------------------

#define B_    64
#define T_    512
#define H_    1024
#define NBLK  64
#define COLS  16
#define KSTEPS 32   // H_/32

typedef __attribute__((ext_vector_type(8))) __bf16 bf16x8;
typedef __attribute__((ext_vector_type(4))) float f32x4;
typedef __attribute__((ext_vector_type(4))) unsigned uint32x4;

static __device__ __forceinline__ unsigned f2bf_bits(float f) {
    unsigned u = __float_as_uint(f);
    return (u + 0x7FFFu + ((u >> 16) & 1u)) >> 16;   // RNE, finite inputs
}

static __device__ __forceinline__ float fast_tanh(float x) {
    x = fminf(fmaxf(x, -15.f), 15.f);
    const float e = __expf(2.f * x);                  // finite after clamp
    return 1.f - 2.f * __builtin_amdgcn_rcpf(e + 1.f);
}

// plain (L1-cacheable) loads, volatile asm so all issue back-to-back into one
// vmcnt wait group; consumption only after s_waitcnt vmcnt(0)+sched_barrier.
#define SLOAD(dst, base, BOFF)                                                \
    asm volatile("global_load_dwordx4 %0, %1, off offset:%2"                  \
                 : "=&v"(dst) : "v"(base), "n"(BOFF))
#define ULOAD(dst, base)                                                      \
    asm volatile("global_load_dword %0, %1, off"                              \
                 : "=&v"(dst) : "v"(base))

// ------------------------------- u GEMM ------------------------------------
// C[m][n] = sum_k X[m][k]*Win[n][k] + bin[n]; M=32768 N=1024 K=512 (verified)
#define BM 128
#define BN 128
#define BKK 32
#define LDT 40

__global__ __launch_bounds__(256)
void u_gemm(const float* __restrict__ X, const float* __restrict__ Win,
            const float* __restrict__ bin, float* __restrict__ U) {
    __shared__ unsigned short Al[BM][LDT];
    __shared__ unsigned short Bl[BN][LDT];
    const int tid = threadIdx.x;
    const int m0 = blockIdx.y * BM;
    const int n0 = blockIdx.x * BN;
    const int l  = tid & 63;
    const int w  = tid >> 6;
    const int wr = (w >> 1) * 64, wc = (w & 1) * 64;
    const int fr = l & 15, fk = (l >> 4) * 8;

    f32x4 acc[4][4];
#pragma unroll
    for (int m = 0; m < 4; ++m)
#pragma unroll
        for (int n = 0; n < 4; ++n) acc[m][n] = f32x4{0.f, 0.f, 0.f, 0.f};

    const int sr = tid >> 1;
    const int sc = (tid & 1) * 16;

    for (int k0 = 0; k0 < 512; k0 += BKK) {
        const float* ap = X   + (size_t)(m0 + sr) * 512 + k0 + sc;
        const float* bp = Win + (size_t)(n0 + sr) * 512 + k0 + sc;
        float a[16], b[16];
#pragma unroll
        for (int j = 0; j < 4; ++j) {
            *(float4*)&a[j * 4] = *(const float4*)(ap + j * 4);
            *(float4*)&b[j * 4] = *(const float4*)(bp + j * 4);
        }
        __syncthreads();
#pragma unroll
        for (int j = 0; j < 16; ++j) {
            Al[sr][sc + j] = (unsigned short)f2bf_bits(a[j]);
            Bl[sr][sc + j] = (unsigned short)f2bf_bits(b[j]);
        }
        __syncthreads();

        bf16x8 af[4], bf[4];
#pragma unroll
        for (int m = 0; m < 4; ++m)
            af[m] = *(const bf16x8*)&Al[wr + m * 16 + fr][fk];
#pragma unroll
        for (int n = 0; n < 4; ++n)
            bf[n] = *(const bf16x8*)&Bl[wc + n * 16 + fr][fk];
#pragma unroll
        for (int m = 0; m < 4; ++m)
#pragma unroll
            for (int n = 0; n < 4; ++n)
                acc[m][n] = __builtin_amdgcn_mfma_f32_16x16x32_bf16(
                    af[m], bf[n], acc[m][n], 0, 0, 0);
    }

#pragma unroll
    for (int m = 0; m < 4; ++m) {
#pragma unroll
        for (int n = 0; n < 4; ++n) {
            const int col = n0 + wc + n * 16 + fr;
            const float bb = bin[col];
#pragma unroll
            for (int r = 0; r < 4; ++r) {
                const int row = m0 + wr + m * 16 + (l >> 4) * 4 + r;
                U[(size_t)row * 1024 + col] = acc[m][n][r] + bb;
            }
        }
    }
}

// ----------------------------- recurrence ----------------------------------
__global__ __launch_bounds__(256, 1)
void rec_mfma(const float* __restrict__ Wst, float* __restrict__ UY,
              const float* __restrict__ b_state, const float* __restrict__ decay,
              const float* __restrict__ gamma, const float* __restrict__ beta,
              unsigned short* __restrict__ S0, unsigned short* __restrict__ S1,
              float2* __restrict__ P0, float2* __restrict__ P1,
              unsigned* __restrict__ flags) {
    __shared__ __align__(16) unsigned short Wl[128][COLS][8];  // [k/8][col][8] bf16

    const int tid  = threadIdx.x;
    const int bid  = blockIdx.x;
    const int h0   = bid * COLS;
    const int wave = tid >> 6;          // 0..3 -> b-tile
    const int lane = tid & 63;
    const int c    = lane & 15;         // local col = A-frag row = C/D col
    const int rgrp = lane >> 4;         // 0..3 (k-chunk / C/D row group)

    // ---- W slice -> LDS (bf16), loaded exactly once ----
    {
        const int col = tid >> 4;       // 0..15
        const int sub = tid & 15;
        const float* wr_ = Wst + (size_t)(h0 + col) * H_ + sub * 64;
#pragma unroll
        for (int i = 0; i < 8; ++i) {
            float4 f0 = *(const float4*)(wr_ + i * 8);
            float4 f1 = *(const float4*)(wr_ + i * 8 + 4);
            unsigned short* dst = &Wl[sub * 8 + i][col][0];
            dst[0] = (unsigned short)f2bf_bits(f0.x);
            dst[1] = (unsigned short)f2bf_bits(f0.y);
            dst[2] = (unsigned short)f2bf_bits(f0.z);
            dst[3] = (unsigned short)f2bf_bits(f0.w);
            dst[4] = (unsigned short)f2bf_bits(f1.x);
            dst[5] = (unsigned short)f2bf_bits(f1.y);
            dst[6] = (unsigned short)f2bf_bits(f1.z);
            dst[7] = (unsigned short)f2bf_bits(f1.w);
        }
    }

    const float d_c  = 1.f / (1.f + __expf(-decay[h0 + c]));
    const float od_c = 1.f - d_c;
    const float bs_c = b_state[h0 + c];
    const float g_c  = gamma[h0 + c];
    const float be_c = beta[h0 + c];

    float sold[4] = {0.f, 0.f, 0.f, 0.f};
    int brow[4];
#pragma unroll
    for (int r = 0; r < 4; ++r) brow[r] = wave * 16 + rgrp * 4 + r;

    const int prow = tid >> 2, pj = tid & 3;

    // prologue: u for t=0 (plain loads; consumed after first vmcnt(0))
    float uun[4];
#pragma unroll
    for (int r = 0; r < 4; ++r)
        uun[r] = UY[(size_t)brow[r] * T_ * H_ + h0 + c];
    float uu[4];

    __syncthreads();

    for (int t = 0; t < T_; ++t) {
        const unsigned short* Sr = (t & 1) ? S1 : S0;
        unsigned short*       Sw = (t & 1) ? S0 : S1;
        float2*               Pw = (t & 1) ? P1 : P0;

        // ---- bulk-issue this step's loads: 8 Pr + 32 S, one wait group ----
        asm volatile("" ::: "memory");         // order after prev acquire fence
        uint32x4 prw[8];
        if (t > 0) {
            const float2* Pr = ((t - 1) & 1) ? P1 : P0;
            const float2* pb = Pr + prow * NBLK + pj * 16;
            SLOAD(prw[0], pb, 0);   SLOAD(prw[1], pb, 16);
            SLOAD(prw[2], pb, 32);  SLOAD(prw[3], pb, 48);
            SLOAD(prw[4], pb, 64);  SLOAD(prw[5], pb, 80);
            SLOAD(prw[6], pb, 96);  SLOAD(prw[7], pb, 112);
        }
        uint32x4 sa[KSTEPS];
        const unsigned short* sbase =
            Sr + (size_t)(wave * 16 + c) * H_ + rgrp * 8;
#pragma unroll
        for (int kk = 0; kk < KSTEPS; ++kk)
            SLOAD(sa[kk], sbase, kk * 64);

        asm volatile("s_waitcnt vmcnt(0)" ::: "memory");
        __builtin_amdgcn_sched_barrier(0);

        // u for this step (landed with the wait above; loaded last poll phase)
#pragma unroll
        for (int r = 0; r < 4; ++r) uu[r] = uun[r];

        // ---- LN finish for y_{t-1}: values into regs, stored in poll phase
        float yv[4];
        if (t > 0) {
            float s1 = 0.f, s2 = 0.f;
#pragma unroll
            for (int k = 0; k < 8; ++k) {
                const f32x4 q = __builtin_bit_cast(f32x4, prw[k]);
                s1 += q[0] + q[2];
                s2 += q[1] + q[3];
            }
            s1 += __shfl_xor(s1, 1); s2 += __shfl_xor(s2, 1);
            s1 += __shfl_xor(s1, 2); s2 += __shfl_xor(s2, 2);
            const float mu_l  = s1 * (1.f / (float)H_);
            const float var_l = s2 * (1.f / (float)H_) - mu_l * mu_l;
            const float rs_l  = rsqrtf(var_l + 1e-5f);
#pragma unroll
            for (int r = 0; r < 4; ++r) {
                const float mu_r = __shfl(mu_l, rgrp * 16 + r * 4);
                const float rs_r = __shfl(rs_l, rgrp * 16 + r * 4);
                yv[r] = (sold[r] - mu_r) * rs_r * g_c + be_c;
            }
        }

        // ---- MFMA: acc = s_t @ Wslice^T (4 parallel chains) ----
        f32x4 a0 = {0.f, 0.f, 0.f, 0.f}, a1 = a0, a2 = a0, a3 = a0;
#pragma unroll
        for (int kk = 0; kk < KSTEPS; kk += 4) {
            a0 = __builtin_amdgcn_mfma_f32_16x16x32_bf16(
                __builtin_bit_cast(bf16x8, sa[kk + 0]),
                *(const bf16x8*)(&Wl[(kk + 0) * 4 + rgrp][c][0]), a0, 0, 0, 0);
            a1 = __builtin_amdgcn_mfma_f32_16x16x32_bf16(
                __builtin_bit_cast(bf16x8, sa[kk + 1]),
                *(const bf16x8*)(&Wl[(kk + 1) * 4 + rgrp][c][0]), a1, 0, 0, 0);
            a2 = __builtin_amdgcn_mfma_f32_16x16x32_bf16(
                __builtin_bit_cast(bf16x8, sa[kk + 2]),
                *(const bf16x8*)(&Wl[(kk + 2) * 4 + rgrp][c][0]), a2, 0, 0, 0);
            a3 = __builtin_amdgcn_mfma_f32_16x16x32_bf16(
                __builtin_bit_cast(bf16x8, sa[kk + 3]),
                *(const bf16x8*)(&Wl[(kk + 3) * 4 + rgrp][c][0]), a3, 0, 0, 0);
        }
        const f32x4 acc = (a0 + a1) + (a2 + a3);

        // ---- state update, publish bf16 state + fp32 partials ----
        float p1v[4], p2v[4];
#pragma unroll
        for (int r = 0; r < 4; ++r) {
            const float pre = acc[r] + uu[r] + bs_c;
            const float sn  = d_c * sold[r] + od_c * fast_tanh(pre);
            sold[r] = sn;
            p1v[r] = sn;
            p2v[r] = sn * sn;
            __hip_atomic_store(&Sw[(size_t)brow[r] * H_ + h0 + c],
                               (unsigned short)f2bf_bits(sn),
                               __ATOMIC_RELAXED, __HIP_MEMORY_SCOPE_AGENT);
        }
#pragma unroll
        for (int o = 1; o < 16; o <<= 1) {
#pragma unroll
            for (int r = 0; r < 4; ++r) {
                p1v[r] += __shfl_xor(p1v[r], o);
                p2v[r] += __shfl_xor(p2v[r], o);
            }
        }
        if (c == 0) {
#pragma unroll
            for (int r = 0; r < 4; ++r) {
                const float2 pv = {p1v[r], p2v[r]};
                __hip_atomic_store((unsigned long long*)&Pw[brow[r] * NBLK + bid],
                                   __builtin_bit_cast(unsigned long long, pv),
                                   __ATOMIC_RELAXED, __HIP_MEMORY_SCOPE_AGENT);
            }
        }

        // ---- drain ONLY S/P stores, then raw barrier + flag ----
        asm volatile("s_waitcnt vmcnt(0)" ::: "memory");
        __builtin_amdgcn_s_barrier();
        if (tid == 0)
            __hip_atomic_store(&flags[bid], (unsigned)(t + 1),
                               __ATOMIC_RELAXED, __HIP_MEMORY_SCOPE_AGENT);

        // ---- poll-window work: y_{t-1} stores + u_{t+1} prefetch in flight
        if (t > 0) {
#pragma unroll
            for (int r = 0; r < 4; ++r)
                UY[((size_t)brow[r] * T_ + (t - 1)) * H_ + h0 + c] = yv[r];
        }
        {
            const int tn = (t + 1 < T_) ? (t + 1) : t;
#pragma unroll
            for (int r = 0; r < 4; ++r) {
                const float* ub = UY + ((size_t)brow[r] * T_ + tn) * H_ + h0 + c;
                ULOAD(uun[r], ub);
            }
        }

        if (wave == 0) {
            const unsigned tgt = (unsigned)(t + 1);
            for (;;) {
                const unsigned v = __hip_atomic_load(&flags[lane],
                                                     __ATOMIC_RELAXED,
                                                     __HIP_MEMORY_SCOPE_AGENT);
                if (__ballot(v >= tgt) == ~0ull) break;
                __builtin_amdgcn_s_sleep(1);
            }
            __builtin_amdgcn_fence(__ATOMIC_ACQUIRE, "agent");
        }
        __builtin_amdgcn_s_barrier();
    }

    // ---- epilogue: y_{T-1} = LN(s_T) from partials published at t=T-1 ----
    {
        const float2* Pr = ((T_ - 1) & 1) ? P1 : P0;
        const float2* pb = Pr + prow * NBLK + pj * 16;
        uint32x4 prw[8];
        SLOAD(prw[0], pb, 0);   SLOAD(prw[1], pb, 16);
        SLOAD(prw[2], pb, 32);  SLOAD(prw[3], pb, 48);
        SLOAD(prw[4], pb, 64);  SLOAD(prw[5], pb, 80);
        SLOAD(prw[6], pb, 96);  SLOAD(prw[7], pb, 112);
        asm volatile("s_waitcnt vmcnt(0)" ::: "memory");
        __builtin_amdgcn_sched_barrier(0);
        float s1 = 0.f, s2 = 0.f;
#pragma unroll
        for (int k = 0; k < 8; ++k) {
            const f32x4 q = __builtin_bit_cast(f32x4, prw[k]);
            s1 += q[0] + q[2];
            s2 += q[1] + q[3];
        }
        s1 += __shfl_xor(s1, 1); s2 += __shfl_xor(s2, 1);
        s1 += __shfl_xor(s1, 2); s2 += __shfl_xor(s2, 2);
        const float mu_l  = s1 * (1.f / (float)H_);
        const float var_l = s2 * (1.f / (float)H_) - mu_l * mu_l;
        const float rs_l  = rsqrtf(var_l + 1e-5f);
#pragma unroll
        for (int r = 0; r < 4; ++r) {
            const float mu_r = __shfl(mu_l, rgrp * 16 + r * 4);
            const float rs_r = __shfl(rs_l, rgrp * 16 + r * 4);
            UY[((size_t)brow[r] * T_ + (T_ - 1)) * H_ + h0 + c] =
                (sold[r] - mu_r) * rs_r * g_c + be_c;
        }
    }
}

// ---------------------------------------------------------------------------
extern "C" void kernel_launch(void* const* d_in, const int* in_sizes, int n_in,
                              void* d_out, int out_size, void* d_ws, size_t ws_size,
                              hipStream_t stream) {
    const float* x   = (const float*)d_in[0];
    const float* Win = (const float*)d_in[1];
    const float* bin = (const float*)d_in[2];
    const float* Wst = (const float*)d_in[3];
    const float* bst = (const float*)d_in[4];
    const float* dec = (const float*)d_in[5];
    const float* lng = (const float*)d_in[6];
    const float* lnb = (const float*)d_in[7];
    float* out = (float*)d_out;

    unsigned char* ws = (unsigned char*)d_ws;
    unsigned*       flags = (unsigned*)ws;                         // 256 B
    unsigned short* S0 = (unsigned short*)(ws + 4096);             // 128 KB
    unsigned short* S1 = (unsigned short*)(ws + 4096 + 131072);    // 128 KB
    float2*         P0 = (float2*)(ws + 4096 + 262144);            // 32 KB
    float2*         P1 = (float2*)(ws + 4096 + 262144 + 32768);    // 32 KB

    // zero flags + S0 (initial state); S1/P0/P1 are written before first read
    hipMemsetAsync(d_ws, 0, 4096 + 131072, stream);
    u_gemm<<<dim3(8, 256), 256, 0, stream>>>(x, Win, bin, out);
    rec_mfma<<<NBLK, 256, 0, stream>>>(Wst, out, bst, dec, lng, lnb,
                                       S0, S1, P0, P1, flags);
}

// Round 11
// 3824.059 us; speedup vs baseline: 1.2144x; 1.2144x over previous
//
#include <hip/hip_runtime.h>
#include <hip/hip_bf16.h>

// ---------------------------------------------------------------------------
// StateSpaceLite on MI355X.
//   u = x@W_in^T + b_in            (bf16 MFMA GEMM -> d_out, in place)
//   scan over t: driven = tanh(u_t + s@W_state^T + b_state)
//                s' = d*s + (1-d)*driven ; y_t = LN(s')*gamma + beta
// Round-11: 4 INDEPENDENT groups of 16 blocks. Group r owns batch rows
// [16r,16r+16); block (r,c) computes cols [64c,64c+64) for those rows.
// Per step a block reads only its group's 32KB state slice (was 128KB),
// barrier spans 16 blocks (was 64), groups never sync with each other.
// W slice (64 cols x 1024) in LDS (128KB). LN stats computed from the
// loaded bf16 S words (round-3-proven). Exchange protocol unchanged from
// proven rounds 5/8/10: agent-relaxed bf16 state stores, flag barrier,
// one agent acquire fence per block per step.
// ---------------------------------------------------------------------------

#define B_    64
#define T_    512
#define H_    1024
#define GCOLS 64     // cols per block
#define KSTEPS 32    // H_/32

typedef __attribute__((ext_vector_type(8))) __bf16 bf16x8;
typedef __attribute__((ext_vector_type(4))) float f32x4;
typedef __attribute__((ext_vector_type(4))) unsigned uint32x4;

static __device__ __forceinline__ unsigned f2bf_bits(float f) {
    unsigned u = __float_as_uint(f);
    return (u + 0x7FFFu + ((u >> 16) & 1u)) >> 16;   // RNE, finite inputs
}
static __device__ __forceinline__ float blo(unsigned v) { return __uint_as_float(v << 16); }
static __device__ __forceinline__ float bhi(unsigned v) { return __uint_as_float(v & 0xFFFF0000u); }

static __device__ __forceinline__ float fast_tanh(float x) {
    x = fminf(fmaxf(x, -15.f), 15.f);
    const float e = __expf(2.f * x);                  // finite after clamp
    return 1.f - 2.f * __builtin_amdgcn_rcpf(e + 1.f);
}

#define SLOAD(dst, base, BOFF)                                                \
    asm volatile("global_load_dwordx4 %0, %1, off offset:%2"                  \
                 : "=&v"(dst) : "v"(base), "n"(BOFF))
#define ULOAD(dst, base)                                                      \
    asm volatile("global_load_dword %0, %1, off"                              \
                 : "=&v"(dst) : "v"(base))

// ------------------------------- u GEMM ------------------------------------
// C[m][n] = sum_k X[m][k]*Win[n][k] + bin[n]; M=32768 N=1024 K=512 (verified)
#define BM 128
#define BN 128
#define BKK 32
#define LDT 40

__global__ __launch_bounds__(256)
void u_gemm(const float* __restrict__ X, const float* __restrict__ Win,
            const float* __restrict__ bin, float* __restrict__ U) {
    __shared__ unsigned short Al[BM][LDT];
    __shared__ unsigned short Bl[BN][LDT];
    const int tid = threadIdx.x;
    const int m0 = blockIdx.y * BM;
    const int n0 = blockIdx.x * BN;
    const int l  = tid & 63;
    const int w  = tid >> 6;
    const int wr = (w >> 1) * 64, wc = (w & 1) * 64;
    const int fr = l & 15, fk = (l >> 4) * 8;

    f32x4 acc[4][4];
#pragma unroll
    for (int m = 0; m < 4; ++m)
#pragma unroll
        for (int n = 0; n < 4; ++n) acc[m][n] = f32x4{0.f, 0.f, 0.f, 0.f};

    const int sr = tid >> 1;
    const int sc = (tid & 1) * 16;

    for (int k0 = 0; k0 < 512; k0 += BKK) {
        const float* ap = X   + (size_t)(m0 + sr) * 512 + k0 + sc;
        const float* bp = Win + (size_t)(n0 + sr) * 512 + k0 + sc;
        float a[16], b[16];
#pragma unroll
        for (int j = 0; j < 4; ++j) {
            *(float4*)&a[j * 4] = *(const float4*)(ap + j * 4);
            *(float4*)&b[j * 4] = *(const float4*)(bp + j * 4);
        }
        __syncthreads();
#pragma unroll
        for (int j = 0; j < 16; ++j) {
            Al[sr][sc + j] = (unsigned short)f2bf_bits(a[j]);
            Bl[sr][sc + j] = (unsigned short)f2bf_bits(b[j]);
        }
        __syncthreads();

        bf16x8 af[4], bf[4];
#pragma unroll
        for (int m = 0; m < 4; ++m)
            af[m] = *(const bf16x8*)&Al[wr + m * 16 + fr][fk];
#pragma unroll
        for (int n = 0; n < 4; ++n)
            bf[n] = *(const bf16x8*)&Bl[wc + n * 16 + fr][fk];
#pragma unroll
        for (int m = 0; m < 4; ++m)
#pragma unroll
            for (int n = 0; n < 4; ++n)
                acc[m][n] = __builtin_amdgcn_mfma_f32_16x16x32_bf16(
                    af[m], bf[n], acc[m][n], 0, 0, 0);
    }

#pragma unroll
    for (int m = 0; m < 4; ++m) {
#pragma unroll
        for (int n = 0; n < 4; ++n) {
            const int col = n0 + wc + n * 16 + fr;
            const float bb = bin[col];
#pragma unroll
            for (int r = 0; r < 4; ++r) {
                const int row = m0 + wr + m * 16 + (l >> 4) * 4 + r;
                U[(size_t)row * 1024 + col] = acc[m][n][r] + bb;
            }
        }
    }
}

// ----------------------------- recurrence ----------------------------------
__global__ __launch_bounds__(256, 1)
void rec_grp(const float* __restrict__ Wst, float* __restrict__ UY,
             const float* __restrict__ b_state, const float* __restrict__ decay,
             const float* __restrict__ gamma, const float* __restrict__ beta,
             unsigned short* __restrict__ S0, unsigned short* __restrict__ S1,
             unsigned* __restrict__ flags) {
    __shared__ __align__(16) unsigned short Wl[128][GCOLS][8];   // 128 KB

    const int tid  = threadIdx.x;
    const int bid  = blockIdx.x;
    const int rg   = bid >> 4;              // row group 0..3
    const int cb   = bid & 15;              // col block 0..15
    const int row0 = rg * 16;               // batch-row base of the group
    const int h0   = cb * GCOLS;            // col base of this block
    const int wave = tid >> 6;              // 0..3 -> col sub-tile
    const int lane = tid & 63;
    const int c    = lane & 15;             // A-row / C-col within 16
    const int rgrp = lane >> 4;             // k-chunk / C-row group
    const int mycol = h0 + wave * 16 + c;   // this thread's output col

    // ---- W slice (64 cols x 1024) -> LDS bf16, once ----
    {
        const int col = tid >> 2;           // 0..63
        const int sub = tid & 3;            // k quarter (256 k each)
        const float* wr_ = Wst + (size_t)(h0 + col) * H_ + sub * 256;
#pragma unroll
        for (int i = 0; i < 32; ++i) {
            float4 f0 = *(const float4*)(wr_ + i * 8);
            float4 f1 = *(const float4*)(wr_ + i * 8 + 4);
            unsigned short* dst = &Wl[sub * 32 + i][col][0];
            dst[0] = (unsigned short)f2bf_bits(f0.x);
            dst[1] = (unsigned short)f2bf_bits(f0.y);
            dst[2] = (unsigned short)f2bf_bits(f0.z);
            dst[3] = (unsigned short)f2bf_bits(f0.w);
            dst[4] = (unsigned short)f2bf_bits(f1.x);
            dst[5] = (unsigned short)f2bf_bits(f1.y);
            dst[6] = (unsigned short)f2bf_bits(f1.z);
            dst[7] = (unsigned short)f2bf_bits(f1.w);
        }
    }

    const float d_c  = 1.f / (1.f + __expf(-decay[mycol]));
    const float od_c = 1.f - d_c;
    const float bs_c = b_state[mycol];
    const float g_c  = gamma[mycol];
    const float be_c = beta[mycol];

    float sold[4] = {0.f, 0.f, 0.f, 0.f};
    int brow[4];                            // global batch rows of the 4 accs
#pragma unroll
    for (int r = 0; r < 4; ++r) brow[r] = row0 + rgrp * 4 + r;

    // u for t=0 (plain loads, consumed after first vmcnt(0))
    float uun[4];
#pragma unroll
    for (int r = 0; r < 4; ++r)
        uun[r] = UY[(size_t)brow[r] * T_ * H_ + mycol];
    float uu[4];

    __syncthreads();

    for (int t = 0; t < T_; ++t) {
        const unsigned short* Sr = (t & 1) ? S1 : S0;
        unsigned short*       Sw = (t & 1) ? S0 : S1;

        // ---- issue the group's S slice: 32 x dwordx4, one wait group ----
        asm volatile("" ::: "memory");      // order after prev acquire fence
        uint32x4 sa[KSTEPS];
        const unsigned short* sbase =
            Sr + (size_t)(row0 + c) * H_ + rgrp * 8;
#pragma unroll
        for (int kk = 0; kk < KSTEPS; ++kk)
            SLOAD(sa[kk], sbase, kk * 64);

        asm volatile("s_waitcnt vmcnt(0)" ::: "memory");
        __builtin_amdgcn_sched_barrier(0);

#pragma unroll
        for (int r = 0; r < 4; ++r) uu[r] = uun[r];

        // ---- LN stats of s_t from the loaded bf16 words (row = row0+c) ----
        float s1 = 0.f, s2 = 0.f;
#pragma unroll
        for (int kk = 0; kk < KSTEPS; ++kk) {
            const uint32x4 w4 = sa[kk];
            const float e0 = blo(w4[0]), e1 = bhi(w4[0]);
            const float e2 = blo(w4[1]), e3 = bhi(w4[1]);
            const float e4 = blo(w4[2]), e5 = bhi(w4[2]);
            const float e6 = blo(w4[3]), e7 = bhi(w4[3]);
            s1 += ((e0 + e1) + (e2 + e3)) + ((e4 + e5) + (e6 + e7));
            s2 = fmaf(e0, e0, s2); s2 = fmaf(e1, e1, s2);
            s2 = fmaf(e2, e2, s2); s2 = fmaf(e3, e3, s2);
            s2 = fmaf(e4, e4, s2); s2 = fmaf(e5, e5, s2);
            s2 = fmaf(e6, e6, s2); s2 = fmaf(e7, e7, s2);
        }
        // 4 k-quarters of a row live at lanes c, c+16, c+32, c+48
        s1 += __shfl_xor(s1, 16); s2 += __shfl_xor(s2, 16);
        s1 += __shfl_xor(s1, 32); s2 += __shfl_xor(s2, 32);
        const float mu_l = s1 * (1.f / (float)H_);
        const float rs_l = rsqrtf(s2 * (1.f / (float)H_) - mu_l * mu_l + 1e-5f);

        // y_{t-1} = LN(s_t) into regs (stored in the poll window)
        float yv[4];
        if (t > 0) {
#pragma unroll
            for (int r = 0; r < 4; ++r) {
                const int lr = rgrp * 4 + r;        // local row 0..15
                const float mu_r = __shfl(mu_l, lr);
                const float rs_r = __shfl(rs_l, lr);
                yv[r] = (sold[r] - mu_r) * rs_r * g_c + be_c;
            }
        }

        // ---- MFMA: acc = s_t(group) @ Wslice^T (4 parallel chains) ----
        f32x4 a0 = {0.f, 0.f, 0.f, 0.f}, a1 = a0, a2 = a0, a3 = a0;
#pragma unroll
        for (int kk = 0; kk < KSTEPS; kk += 4) {
            a0 = __builtin_amdgcn_mfma_f32_16x16x32_bf16(
                __builtin_bit_cast(bf16x8, sa[kk + 0]),
                *(const bf16x8*)(&Wl[(kk + 0) * 4 + rgrp][wave * 16 + c][0]), a0, 0, 0, 0);
            a1 = __builtin_amdgcn_mfma_f32_16x16x32_bf16(
                __builtin_bit_cast(bf16x8, sa[kk + 1]),
                *(const bf16x8*)(&Wl[(kk + 1) * 4 + rgrp][wave * 16 + c][0]), a1, 0, 0, 0);
            a2 = __builtin_amdgcn_mfma_f32_16x16x32_bf16(
                __builtin_bit_cast(bf16x8, sa[kk + 2]),
                *(const bf16x8*)(&Wl[(kk + 2) * 4 + rgrp][wave * 16 + c][0]), a2, 0, 0, 0);
            a3 = __builtin_amdgcn_mfma_f32_16x16x32_bf16(
                __builtin_bit_cast(bf16x8, sa[kk + 3]),
                *(const bf16x8*)(&Wl[(kk + 3) * 4 + rgrp][wave * 16 + c][0]), a3, 0, 0, 0);
        }
        const f32x4 acc = (a0 + a1) + (a2 + a3);

        // ---- state update, publish bf16 state slice ----
#pragma unroll
        for (int r = 0; r < 4; ++r) {
            const float pre = acc[r] + uu[r] + bs_c;
            const float sn  = d_c * sold[r] + od_c * fast_tanh(pre);
            sold[r] = sn;
            __hip_atomic_store(&Sw[(size_t)brow[r] * H_ + mycol],
                               (unsigned short)f2bf_bits(sn),
                               __ATOMIC_RELAXED, __HIP_MEMORY_SCOPE_AGENT);
        }

        // ---- drain S stores, barrier, flag ----
        asm volatile("s_waitcnt vmcnt(0)" ::: "memory");
        __builtin_amdgcn_s_barrier();
        if (tid == 0)
            __hip_atomic_store(&flags[bid], (unsigned)(t + 1),
                               __ATOMIC_RELAXED, __HIP_MEMORY_SCOPE_AGENT);

        // ---- poll-window work: y stores + u_{t+1} prefetch fly here ----
        if (t > 0) {
#pragma unroll
            for (int r = 0; r < 4; ++r)
                UY[((size_t)brow[r] * T_ + (t - 1)) * H_ + mycol] = yv[r];
        }
        {
            const int tn = (t + 1 < T_) ? (t + 1) : t;
#pragma unroll
            for (int r = 0; r < 4; ++r) {
                const float* ub = UY + ((size_t)brow[r] * T_ + tn) * H_ + mycol;
                ULOAD(uun[r], ub);
            }
        }

        if (wave == 0) {
            const unsigned tgt = (unsigned)(t + 1);
            const unsigned* fp = flags + rg * 16 + (lane & 15);
            for (;;) {
                const unsigned v = __hip_atomic_load(fp, __ATOMIC_RELAXED,
                                                     __HIP_MEMORY_SCOPE_AGENT);
                if (__ballot((lane >= 16) || (v >= tgt)) == ~0ull) break;
                __builtin_amdgcn_s_sleep(1);
            }
            __builtin_amdgcn_fence(__ATOMIC_ACQUIRE, "agent");
        }
        __builtin_amdgcn_s_barrier();
    }

    // ---- epilogue: y_{T-1} = LN(s_T); s_T is in S0 (T_ even) ----
    {
        const unsigned short* Sr = (T_ & 1) ? S1 : S0;
        uint32x4 sa[KSTEPS];
        const unsigned short* sbase =
            Sr + (size_t)(row0 + c) * H_ + rgrp * 8;
#pragma unroll
        for (int kk = 0; kk < KSTEPS; ++kk)
            SLOAD(sa[kk], sbase, kk * 64);
        asm volatile("s_waitcnt vmcnt(0)" ::: "memory");
        __builtin_amdgcn_sched_barrier(0);
        float s1 = 0.f, s2 = 0.f;
#pragma unroll
        for (int kk = 0; kk < KSTEPS; ++kk) {
            const uint32x4 w4 = sa[kk];
            const float e0 = blo(w4[0]), e1 = bhi(w4[0]);
            const float e2 = blo(w4[1]), e3 = bhi(w4[1]);
            const float e4 = blo(w4[2]), e5 = bhi(w4[2]);
            const float e6 = blo(w4[3]), e7 = bhi(w4[3]);
            s1 += ((e0 + e1) + (e2 + e3)) + ((e4 + e5) + (e6 + e7));
            s2 = fmaf(e0, e0, s2); s2 = fmaf(e1, e1, s2);
            s2 = fmaf(e2, e2, s2); s2 = fmaf(e3, e3, s2);
            s2 = fmaf(e4, e4, s2); s2 = fmaf(e5, e5, s2);
            s2 = fmaf(e6, e6, s2); s2 = fmaf(e7, e7, s2);
        }
        s1 += __shfl_xor(s1, 16); s2 += __shfl_xor(s2, 16);
        s1 += __shfl_xor(s1, 32); s2 += __shfl_xor(s2, 32);
        const float mu_l = s1 * (1.f / (float)H_);
        const float rs_l = rsqrtf(s2 * (1.f / (float)H_) - mu_l * mu_l + 1e-5f);
#pragma unroll
        for (int r = 0; r < 4; ++r) {
            const int lr = rgrp * 4 + r;
            const float mu_r = __shfl(mu_l, lr);
            const float rs_r = __shfl(rs_l, lr);
            UY[((size_t)brow[r] * T_ + (T_ - 1)) * H_ + mycol] =
                (sold[r] - mu_r) * rs_r * g_c + be_c;
        }
    }
}

// ---------------------------------------------------------------------------
extern "C" void kernel_launch(void* const* d_in, const int* in_sizes, int n_in,
                              void* d_out, int out_size, void* d_ws, size_t ws_size,
                              hipStream_t stream) {
    const float* x   = (const float*)d_in[0];
    const float* Win = (const float*)d_in[1];
    const float* bin = (const float*)d_in[2];
    const float* Wst = (const float*)d_in[3];
    const float* bst = (const float*)d_in[4];
    const float* dec = (const float*)d_in[5];
    const float* lng = (const float*)d_in[6];
    const float* lnb = (const float*)d_in[7];
    float* out = (float*)d_out;

    unsigned char* ws = (unsigned char*)d_ws;
    unsigned*       flags = (unsigned*)ws;                         // 256 B
    unsigned short* S0 = (unsigned short*)(ws + 4096);             // 128 KB
    unsigned short* S1 = (unsigned short*)(ws + 4096 + 131072);    // 128 KB

    // zero flags + S0 (initial state); S1 is written before first read
    hipMemsetAsync(d_ws, 0, 4096 + 131072, stream);
    u_gemm<<<dim3(8, 256), 256, 0, stream>>>(x, Win, bin, out);
    rec_grp<<<64, 256, 0, stream>>>(Wst, out, bst, dec, lng, lnb, S0, S1, flags);
}

// Round 13
// 2241.979 us; speedup vs baseline: 2.0714x; 1.7057x over previous
//
#include <hip/hip_runtime.h>
#include <hip/hip_bf16.h>

// ---------------------------------------------------------------------------
// StateSpaceLite on MI355X.
//   u = x@W_in^T + b_in            (bf16 MFMA GEMM -> d_out, in place)
//   scan over t: driven = tanh(u_t + s@W_state^T + b_state)
//                s' = d*s + (1-d)*driven ; y_t = LN(s')*gamma + beta
// Round-12: SELF-VERIFYING TAGGED STATE - no flags, no drains, no barriers across
// blocks. State word u32 = (step_tag<<16)|bf16. Writers fire relaxed agent
// stores and proceed. Readers: {acquire fence; bulk load; u32-min tag check;
// retry if stale}. Triple-buffered (t%3) so skew<2 can never overwrite data
// still being read (tag dependency self-throttles skew). 4 groups x 16 blocks
// as in round 11; each wave loads 1/4 of the slice, shares via XOR-swizzled
// LDS (32KB) next to the 128KB W slice (163840 B dynamic LDS).
// ---------------------------------------------------------------------------

#define B_    64
#define T_    512
#define H_    1024
#define GCOLS 64

typedef __attribute__((ext_vector_type(8))) __bf16 bf16x8;
typedef __attribute__((ext_vector_type(4))) float f32x4;
typedef __attribute__((ext_vector_type(4))) unsigned uint32x4;

static __device__ __forceinline__ unsigned f2bf_bits(float f) {
    unsigned u = __float_as_uint(f);
    return (u + 0x7FFFu + ((u >> 16) & 1u)) >> 16;   // RNE, finite inputs
}

static __device__ __forceinline__ float fast_tanh(float x) {
    x = fminf(fmaxf(x, -15.f), 15.f);
    const float e = __expf(2.f * x);                  // finite after clamp
    return 1.f - 2.f * __builtin_amdgcn_rcpf(e + 1.f);
}

#define SLOAD(dst, base, BOFF)                                                \
    asm volatile("global_load_dwordx4 %0, %1, off offset:%2"                  \
                 : "=&v"(dst) : "v"(base), "n"(BOFF))
#define ULOAD(dst, base)                                                      \
    asm volatile("global_load_dword %0, %1, off"                              \
                 : "=&v"(dst) : "v"(base))

// ------------------------------- u GEMM ------------------------------------
#define BM 128
#define BN 128
#define BKK 32
#define LDT 40

__global__ __launch_bounds__(256)
void u_gemm(const float* __restrict__ X, const float* __restrict__ Win,
            const float* __restrict__ bin, float* __restrict__ U) {
    __shared__ unsigned short Al[BM][LDT];
    __shared__ unsigned short Bl[BN][LDT];
    const int tid = threadIdx.x;
    const int m0 = blockIdx.y * BM;
    const int n0 = blockIdx.x * BN;
    const int l  = tid & 63;
    const int w  = tid >> 6;
    const int wr = (w >> 1) * 64, wc = (w & 1) * 64;
    const int fr = l & 15, fk = (l >> 4) * 8;

    f32x4 acc[4][4];
#pragma unroll
    for (int m = 0; m < 4; ++m)
#pragma unroll
        for (int n = 0; n < 4; ++n) acc[m][n] = f32x4{0.f, 0.f, 0.f, 0.f};

    const int sr = tid >> 1;
    const int sc = (tid & 1) * 16;

    for (int k0 = 0; k0 < 512; k0 += BKK) {
        const float* ap = X   + (size_t)(m0 + sr) * 512 + k0 + sc;
        const float* bp = Win + (size_t)(n0 + sr) * 512 + k0 + sc;
        float a[16], b[16];
#pragma unroll
        for (int j = 0; j < 4; ++j) {
            *(float4*)&a[j * 4] = *(const float4*)(ap + j * 4);
            *(float4*)&b[j * 4] = *(const float4*)(bp + j * 4);
        }
        __syncthreads();
#pragma unroll
        for (int j = 0; j < 16; ++j) {
            Al[sr][sc + j] = (unsigned short)f2bf_bits(a[j]);
            Bl[sr][sc + j] = (unsigned short)f2bf_bits(b[j]);
        }
        __syncthreads();

        bf16x8 af[4], bf[4];
#pragma unroll
        for (int m = 0; m < 4; ++m)
            af[m] = *(const bf16x8*)&Al[wr + m * 16 + fr][fk];
#pragma unroll
        for (int n = 0; n < 4; ++n)
            bf[n] = *(const bf16x8*)&Bl[wc + n * 16 + fr][fk];
#pragma unroll
        for (int m = 0; m < 4; ++m)
#pragma unroll
            for (int n = 0; n < 4; ++n)
                acc[m][n] = __builtin_amdgcn_mfma_f32_16x16x32_bf16(
                    af[m], bf[n], acc[m][n], 0, 0, 0);
    }

#pragma unroll
    for (int m = 0; m < 4; ++m) {
#pragma unroll
        for (int n = 0; n < 4; ++n) {
            const int col = n0 + wc + n * 16 + fr;
            const float bb = bin[col];
#pragma unroll
            for (int r = 0; r < 4; ++r) {
                const int row = m0 + wr + m * 16 + (l >> 4) * 4 + r;
                U[(size_t)row * 1024 + col] = acc[m][n][r] + bb;
            }
        }
    }
}

// ----------------------------- recurrence ----------------------------------
__global__ __launch_bounds__(256, 1)
void rec_tag(const float* __restrict__ Wst, float* __restrict__ UY,
             const float* __restrict__ b_state, const float* __restrict__ decay,
             const float* __restrict__ gamma, const float* __restrict__ beta,
             unsigned* __restrict__ Sbuf) {
    extern __shared__ __align__(16) unsigned char smem[];
    unsigned short* Wl = (unsigned short*)smem;           // [128][64][8] 128 KB
    unsigned*       Sl = (unsigned*)(smem + 131072);      // [16][512] swizzled 32 KB
    float*          muS = (float*)(smem + 131072);        // reused post-MFMA
    float*          rsS = muS + 16;

    const int tid  = threadIdx.x;
    const int bid  = blockIdx.x;
    const int rg   = bid >> 4;              // group 0..3 (16 batch rows each)
    const int cbk  = bid & 15;              // col block 0..15
    const int h0   = cbk * GCOLS;
    const int wave = tid >> 6;
    const int lane = tid & 63;
    const int c    = lane & 15;             // A-row / C-col / load col-cluster
    const int rgrp = lane >> 4;             // k-chunk / C-row group
    const int mycol = h0 + wave * 16 + c;
    const int lrow  = wave * 4 + rgrp;      // row this lane LOADS (0..15)

    // ---- W slice (64 cols x 1024) -> LDS bf16, once ----
    {
        const int col = tid >> 2;
        const int sub = tid & 3;
        const float* wr_ = Wst + (size_t)(h0 + col) * H_ + sub * 256;
#pragma unroll
        for (int i = 0; i < 32; ++i) {
            float4 f0 = *(const float4*)(wr_ + i * 8);
            float4 f1 = *(const float4*)(wr_ + i * 8 + 4);
            unsigned short* dst = Wl + ((size_t)(sub * 32 + i) * 64 + col) * 8;
            dst[0] = (unsigned short)f2bf_bits(f0.x);
            dst[1] = (unsigned short)f2bf_bits(f0.y);
            dst[2] = (unsigned short)f2bf_bits(f0.z);
            dst[3] = (unsigned short)f2bf_bits(f0.w);
            dst[4] = (unsigned short)f2bf_bits(f1.x);
            dst[5] = (unsigned short)f2bf_bits(f1.y);
            dst[6] = (unsigned short)f2bf_bits(f1.z);
            dst[7] = (unsigned short)f2bf_bits(f1.w);
        }
    }

    const float d_c  = 1.f / (1.f + __expf(-decay[mycol]));
    const float od_c = 1.f - d_c;
    const float bs_c = b_state[mycol];
    const float g_c  = gamma[mycol];
    const float be_c = beta[mycol];

    float sold[4] = {0.f, 0.f, 0.f, 0.f};

    // u for t=0
    float uun[4], uu[4];
#pragma unroll
    for (int r = 0; r < 4; ++r)
        uun[r] = UY[(size_t)(rg * 16 + rgrp * 4 + r) * T_ * H_ + mycol];

    unsigned* const Sg = Sbuf + ((size_t)rg * 3 << 14);   // 3 x [16][1024] u32
    const int swzW = (lrow & 7) << 2;
    const int swzR = (c & 7) << 2;

    __syncthreads();

    for (int t = 0; t < T_; ++t) {
        const unsigned* Sr = Sg + ((size_t)(t % 3) << 14);
        unsigned*       Sw = Sg + ((size_t)((t + 1) % 3) << 14);
        const unsigned tagr = (unsigned)t, tagw = (unsigned)(t + 1);

        __syncthreads();   // prev y-phase LDS reads done before ds_write below

        // ---- tagged load of this wave's 4 rows; retry until fresh ----
        uint32x4 tw[16];
        const unsigned* lb = Sr + (size_t)lrow * 1024 + c * 4;
        for (;;) {
            __builtin_amdgcn_fence(__ATOMIC_ACQUIRE, "agent");
#pragma unroll
            for (int j = 0; j < 16; ++j) SLOAD(tw[j], lb, j * 256);
            asm volatile("s_waitcnt vmcnt(0)" ::: "memory");
            __builtin_amdgcn_sched_barrier(0);
            unsigned mn = 0xFFFFFFFFu;
#pragma unroll
            for (int j = 0; j < 16; ++j) {
                unsigned m01 = tw[j][0] < tw[j][1] ? tw[j][0] : tw[j][1];
                unsigned m23 = tw[j][2] < tw[j][3] ? tw[j][2] : tw[j][3];
                unsigned m = m01 < m23 ? m01 : m23;
                mn = mn < m ? mn : m;
            }
            if (__all((mn >> 16) == tagr)) break;
            __builtin_amdgcn_s_sleep(1);
        }
#pragma unroll
        for (int r = 0; r < 4; ++r) uu[r] = uun[r];   // landed with vmcnt above

        // ---- LN partial stats of this row (64 words/lane, 16 lanes/row) ----
        float s1 = 0.f, s2 = 0.f;
#pragma unroll
        for (int j = 0; j < 16; ++j) {
#pragma unroll
            for (int k = 0; k < 4; ++k) {
                const float v = __uint_as_float(tw[j][k] << 16);
                s1 += v;
                s2 = fmaf(v, v, s2);
            }
        }
        s1 += __shfl_xor(s1, 1); s2 += __shfl_xor(s2, 1);
        s1 += __shfl_xor(s1, 2); s2 += __shfl_xor(s2, 2);
        s1 += __shfl_xor(s1, 4); s2 += __shfl_xor(s2, 4);
        s1 += __shfl_xor(s1, 8); s2 += __shfl_xor(s2, 8);
        const float mu_l = s1 * (1.f / (float)H_);
        const float rs_l = rsqrtf(s2 * (1.f / (float)H_) - mu_l * mu_l + 1e-5f);

        // ---- repack to bf16 pairs, share via swizzled LDS ----
#pragma unroll
        for (int j = 0; j < 16; ++j) {
            const unsigned p0 = __builtin_amdgcn_perm(tw[j][1], tw[j][0], 0x05040100u);
            const unsigned p1 = __builtin_amdgcn_perm(tw[j][3], tw[j][2], 0x05040100u);
            const int idx = (j * 32 + c * 2) ^ swzW;
            *(uint2*)&Sl[lrow * 512 + idx] = uint2{p0, p1};
        }
        __syncthreads();

        // ---- MFMA from LDS: acc = s_t @ Wslice^T ----
        f32x4 a0 = {0.f, 0.f, 0.f, 0.f}, a1 = a0, a2 = a0, a3 = a0;
#pragma unroll
        for (int kk = 0; kk < 32; kk += 4) {
#pragma unroll
            for (int q = 0; q < 4; ++q) {
                const int ai = ((kk + q) * 16 + rgrp * 4) ^ swzR;
                const uint32x4 aw = *(const uint32x4*)&Sl[c * 512 + ai];
                const bf16x8 af = __builtin_bit_cast(bf16x8, aw);
                const bf16x8 bf = *(const bf16x8*)(Wl +
                    ((size_t)((kk + q) * 4 + rgrp) * 64 + wave * 16 + c) * 8);
                if (q == 0) a0 = __builtin_amdgcn_mfma_f32_16x16x32_bf16(af, bf, a0, 0, 0, 0);
                if (q == 1) a1 = __builtin_amdgcn_mfma_f32_16x16x32_bf16(af, bf, a1, 0, 0, 0);
                if (q == 2) a2 = __builtin_amdgcn_mfma_f32_16x16x32_bf16(af, bf, a2, 0, 0, 0);
                if (q == 3) a3 = __builtin_amdgcn_mfma_f32_16x16x32_bf16(af, bf, a3, 0, 0, 0);
            }
        }
        const f32x4 acc = (a0 + a1) + (a2 + a3);

        // ---- update + publish tagged state (relaxed agent stores, no drain) --
        float sprev[4];
#pragma unroll
        for (int r = 0; r < 4; ++r) {
            sprev[r] = sold[r];
            const float pre = acc[r] + uu[r] + bs_c;
            const float sn  = d_c * sold[r] + od_c * fast_tanh(pre);
            sold[r] = sn;
            __hip_atomic_store(&Sw[(size_t)(rgrp * 4 + r) * 1024 + mycol],
                               (tagw << 16) | f2bf_bits(sn),
                               __ATOMIC_RELAXED, __HIP_MEMORY_SCOPE_AGENT);
        }

        // ---- shadow phase: stats exchange + y_{t-1} + u prefetch ----
        __syncthreads();                       // MFMA LDS reads done
        if (c == 0) { muS[lrow] = mu_l; rsS[lrow] = rs_l; }
        __syncthreads();
        if (t > 0) {
#pragma unroll
            for (int r = 0; r < 4; ++r) {
                const int R = rgrp * 4 + r;
                UY[((size_t)(rg * 16 + R) * T_ + (t - 1)) * H_ + mycol] =
                    (sprev[r] - muS[R]) * rsS[R] * g_c + be_c;
            }
        }
        {
            const int tn = (t + 1 < T_) ? (t + 1) : t;
#pragma unroll
            for (int r = 0; r < 4; ++r) {
                const float* ub =
                    UY + ((size_t)(rg * 16 + rgrp * 4 + r) * T_ + tn) * H_ + mycol;
                ULOAD(uun[r], ub);
            }
        }
    }

    // ---- epilogue: y_{T-1} = LN(s_T); read buf[T%3] expecting tag T ----
    {
        const unsigned* Sr = Sg + ((size_t)(T_ % 3) << 14);
        const unsigned tagr = (unsigned)T_;
        uint32x4 tw[16];
        const unsigned* lb = Sr + (size_t)lrow * 1024 + c * 4;
        for (;;) {
            __builtin_amdgcn_fence(__ATOMIC_ACQUIRE, "agent");
#pragma unroll
            for (int j = 0; j < 16; ++j) SLOAD(tw[j], lb, j * 256);
            asm volatile("s_waitcnt vmcnt(0)" ::: "memory");
            __builtin_amdgcn_sched_barrier(0);
            unsigned mn = 0xFFFFFFFFu;
#pragma unroll
            for (int j = 0; j < 16; ++j) {
                unsigned m01 = tw[j][0] < tw[j][1] ? tw[j][0] : tw[j][1];
                unsigned m23 = tw[j][2] < tw[j][3] ? tw[j][2] : tw[j][3];
                unsigned m = m01 < m23 ? m01 : m23;
                mn = mn < m ? mn : m;
            }
            if (__all((mn >> 16) == tagr)) break;
            __builtin_amdgcn_s_sleep(1);
        }
        float s1 = 0.f, s2 = 0.f;
#pragma unroll
        for (int j = 0; j < 16; ++j) {
#pragma unroll
            for (int k = 0; k < 4; ++k) {
                const float v = __uint_as_float(tw[j][k] << 16);
                s1 += v;
                s2 = fmaf(v, v, s2);
            }
        }
        s1 += __shfl_xor(s1, 1); s2 += __shfl_xor(s2, 1);
        s1 += __shfl_xor(s1, 2); s2 += __shfl_xor(s2, 2);
        s1 += __shfl_xor(s1, 4); s2 += __shfl_xor(s2, 4);
        s1 += __shfl_xor(s1, 8); s2 += __shfl_xor(s2, 8);
        const float mu_l = s1 * (1.f / (float)H_);
        const float rs_l = rsqrtf(s2 * (1.f / (float)H_) - mu_l * mu_l + 1e-5f);
        __syncthreads();                      // y-phase of t=511 fully done
        if (c == 0) { muS[lrow] = mu_l; rsS[lrow] = rs_l; }
        __syncthreads();
#pragma unroll
        for (int r = 0; r < 4; ++r) {
            const int R = rgrp * 4 + r;
            UY[((size_t)(rg * 16 + R) * T_ + (T_ - 1)) * H_ + mycol] =
                (sold[r] - muS[R]) * rsS[R] * g_c + be_c;
        }
    }
}

// ---------------------------------------------------------------------------
extern "C" void kernel_launch(void* const* d_in, const int* in_sizes, int n_in,
                              void* d_out, int out_size, void* d_ws, size_t ws_size,
                              hipStream_t stream) {
    const float* x   = (const float*)d_in[0];
    const float* Win = (const float*)d_in[1];
    const float* bin = (const float*)d_in[2];
    const float* Wst = (const float*)d_in[3];
    const float* bst = (const float*)d_in[4];
    const float* dec = (const float*)d_in[5];
    const float* lng = (const float*)d_in[6];
    const float* lnb = (const float*)d_in[7];
    float* out = (float*)d_out;

    unsigned char* ws = (unsigned char*)d_ws;
    unsigned* Sbuf = (unsigned*)(ws + 4096);     // 4 groups x 3 parities x 64KB

    hipFuncSetAttribute(reinterpret_cast<const void*>(rec_tag),
                        hipFuncAttributeMaxDynamicSharedMemorySize, 163840);

    hipMemsetAsync(Sbuf, 0, 4u * 3u * 16u * 1024u * 4u, stream);  // tag0 = s_0
    u_gemm<<<dim3(8, 256), 256, 0, stream>>>(x, Win, bin, out);
    rec_tag<<<64, 256, 163840, stream>>>(Wst, out, bst, dec, lng, lnb, Sbuf);
}

// Round 14
// 1893.302 us; speedup vs baseline: 2.4529x; 1.1842x over previous
//
#include <hip/hip_runtime.h>
#include <hip/hip_bf16.h>

// ---------------------------------------------------------------------------
// StateSpaceLite on MI355X.
//   u = x@W_in^T + b_in            (bf16 MFMA GEMM -> d_out, in place)
//   scan over t: driven = tanh(u_t + s@W_state^T + b_state)
//                s' = d*s + (1-d)*driven ; y_t = LN(s')*gamma + beta
// Round-14: tagged state (round 13) + DIRECT-IC READS. Tagged loads use
// sc0 sc1 (bypass L1+L2, read the coherence point directly) -> no acquire
// fence per attempt, L2 stays warm for u/y. Tag-per-word makes ordering
// irrelevant; freshness is the only requirement. Fallback acquire fence every
// 8th failed attempt bounds staleness (no livelock possible). y_{t-2} stores
// and u_{t+1} loads are issued inside the S-load window (hidden under the IC
// round trip). 4 groups x 16 blocks, W slice in LDS, as round 13.
// ---------------------------------------------------------------------------

#define B_    64
#define T_    512
#define H_    1024
#define GCOLS 64

typedef __attribute__((ext_vector_type(8))) __bf16 bf16x8;
typedef __attribute__((ext_vector_type(4))) float f32x4;
typedef __attribute__((ext_vector_type(4))) unsigned uint32x4;

static __device__ __forceinline__ unsigned f2bf_bits(float f) {
    unsigned u = __float_as_uint(f);
    return (u + 0x7FFFu + ((u >> 16) & 1u)) >> 16;   // RNE, finite inputs
}

static __device__ __forceinline__ float fast_tanh(float x) {
    x = fminf(fmaxf(x, -15.f), 15.f);
    const float e = __expf(2.f * x);                  // finite after clamp
    return 1.f - 2.f * __builtin_amdgcn_rcpf(e + 1.f);
}

// direct-to-IC load (bypass L1+L2): always observes the coherence point
#define SLOADC(dst, base, BOFF)                                               \
    asm volatile("global_load_dwordx4 %0, %1, off offset:%2 sc0 sc1"          \
                 : "=&v"(dst) : "v"(base), "n"(BOFF))
#define ULOAD(dst, base)                                                      \
    asm volatile("global_load_dword %0, %1, off"                              \
                 : "=&v"(dst) : "v"(base))

// ------------------------------- u GEMM ------------------------------------
#define BM 128
#define BN 128
#define BKK 32
#define LDT 40

__global__ __launch_bounds__(256)
void u_gemm(const float* __restrict__ X, const float* __restrict__ Win,
            const float* __restrict__ bin, float* __restrict__ U) {
    __shared__ unsigned short Al[BM][LDT];
    __shared__ unsigned short Bl[BN][LDT];
    const int tid = threadIdx.x;
    const int m0 = blockIdx.y * BM;
    const int n0 = blockIdx.x * BN;
    const int l  = tid & 63;
    const int w  = tid >> 6;
    const int wr = (w >> 1) * 64, wc = (w & 1) * 64;
    const int fr = l & 15, fk = (l >> 4) * 8;

    f32x4 acc[4][4];
#pragma unroll
    for (int m = 0; m < 4; ++m)
#pragma unroll
        for (int n = 0; n < 4; ++n) acc[m][n] = f32x4{0.f, 0.f, 0.f, 0.f};

    const int sr = tid >> 1;
    const int sc = (tid & 1) * 16;

    for (int k0 = 0; k0 < 512; k0 += BKK) {
        const float* ap = X   + (size_t)(m0 + sr) * 512 + k0 + sc;
        const float* bp = Win + (size_t)(n0 + sr) * 512 + k0 + sc;
        float a[16], b[16];
#pragma unroll
        for (int j = 0; j < 4; ++j) {
            *(float4*)&a[j * 4] = *(const float4*)(ap + j * 4);
            *(float4*)&b[j * 4] = *(const float4*)(bp + j * 4);
        }
        __syncthreads();
#pragma unroll
        for (int j = 0; j < 16; ++j) {
            Al[sr][sc + j] = (unsigned short)f2bf_bits(a[j]);
            Bl[sr][sc + j] = (unsigned short)f2bf_bits(b[j]);
        }
        __syncthreads();

        bf16x8 af[4], bf[4];
#pragma unroll
        for (int m = 0; m < 4; ++m)
            af[m] = *(const bf16x8*)&Al[wr + m * 16 + fr][fk];
#pragma unroll
        for (int n = 0; n < 4; ++n)
            bf[n] = *(const bf16x8*)&Bl[wc + n * 16 + fr][fk];
#pragma unroll
        for (int m = 0; m < 4; ++m)
#pragma unroll
            for (int n = 0; n < 4; ++n)
                acc[m][n] = __builtin_amdgcn_mfma_f32_16x16x32_bf16(
                    af[m], bf[n], acc[m][n], 0, 0, 0);
    }

#pragma unroll
    for (int m = 0; m < 4; ++m) {
#pragma unroll
        for (int n = 0; n < 4; ++n) {
            const int col = n0 + wc + n * 16 + fr;
            const float bb = bin[col];
#pragma unroll
            for (int r = 0; r < 4; ++r) {
                const int row = m0 + wr + m * 16 + (l >> 4) * 4 + r;
                U[(size_t)row * 1024 + col] = acc[m][n][r] + bb;
            }
        }
    }
}

// ----------------------------- recurrence ----------------------------------
__global__ __launch_bounds__(256, 1)
void rec_tag2(const float* __restrict__ Wst, float* __restrict__ UY,
              const float* __restrict__ b_state, const float* __restrict__ decay,
              const float* __restrict__ gamma, const float* __restrict__ beta,
              unsigned* __restrict__ Sbuf) {
    extern __shared__ __align__(16) unsigned char smem[];
    unsigned short* Wl = (unsigned short*)smem;           // [128][64][8] 128 KB
    unsigned*       Sl = (unsigned*)(smem + 131072);      // [16][512] swizzled 32 KB
    float*          muS = (float*)(smem + 131072);        // overlays Sl (post-MFMA)
    float*          rsS = muS + 16;

    const int tid  = threadIdx.x;
    const int bid  = blockIdx.x;
    const int rg   = bid >> 4;              // group 0..3 (16 batch rows each)
    const int cbk  = bid & 15;              // col block 0..15
    const int h0   = cbk * GCOLS;
    const int wave = tid >> 6;
    const int lane = tid & 63;
    const int c    = lane & 15;             // A-row / C-col / load col-cluster
    const int rgrp = lane >> 4;             // k-chunk / C-row group
    const int mycol = h0 + wave * 16 + c;
    const int lrow  = wave * 4 + rgrp;      // row this lane LOADS (0..15)

    // ---- W slice (64 cols x 1024) -> LDS bf16, once ----
    {
        const int col = tid >> 2;
        const int sub = tid & 3;
        const float* wr_ = Wst + (size_t)(h0 + col) * H_ + sub * 256;
#pragma unroll
        for (int i = 0; i < 32; ++i) {
            float4 f0 = *(const float4*)(wr_ + i * 8);
            float4 f1 = *(const float4*)(wr_ + i * 8 + 4);
            unsigned short* dst = Wl + ((size_t)(sub * 32 + i) * 64 + col) * 8;
            dst[0] = (unsigned short)f2bf_bits(f0.x);
            dst[1] = (unsigned short)f2bf_bits(f0.y);
            dst[2] = (unsigned short)f2bf_bits(f0.z);
            dst[3] = (unsigned short)f2bf_bits(f0.w);
            dst[4] = (unsigned short)f2bf_bits(f1.x);
            dst[5] = (unsigned short)f2bf_bits(f1.y);
            dst[6] = (unsigned short)f2bf_bits(f1.z);
            dst[7] = (unsigned short)f2bf_bits(f1.w);
        }
    }

    const float d_c  = 1.f / (1.f + __expf(-decay[mycol]));
    const float od_c = 1.f - d_c;
    const float bs_c = b_state[mycol];
    const float g_c  = gamma[mycol];
    const float be_c = beta[mycol];

    float sold[4] = {0.f, 0.f, 0.f, 0.f};
    int brow[4];
#pragma unroll
    for (int r = 0; r < 4; ++r) brow[r] = rg * 16 + rgrp * 4 + r;

    float yv[4] = {0.f, 0.f, 0.f, 0.f};      // y_{t-1} computed at iter t, stored at t+1
    float uun[4], uu[4];
#pragma unroll
    for (int r = 0; r < 4; ++r)
        uun[r] = UY[(size_t)brow[r] * T_ * H_ + mycol];

    unsigned* const Sg = Sbuf + ((size_t)rg * 3 << 14);   // 3 x [16][1024] u32
    const int swzW = (lrow & 7) << 2;
    const int swzR = (c & 7) << 2;

    __syncthreads();

    for (int t = 0; t < T_; ++t) {
        const unsigned* Sr = Sg + ((size_t)(t % 3) << 14);
        unsigned*       Sw = Sg + ((size_t)((t + 1) % 3) << 14);
        const unsigned tagr = (unsigned)t, tagw = (unsigned)(t + 1);

        __syncthreads();   // (A) prev muS reads + prev MFMA Sl reads complete

        // ==== load window: S attempt #1 + y_{t-2} stores + u_{t+1} loads ====
        asm volatile("" ::: "memory");
#pragma unroll
        for (int r = 0; r < 4; ++r) uu[r] = uun[r];        // u_t (landed last iter)

        uint32x4 tw[16];
        const unsigned* lb = Sr + (size_t)lrow * 1024 + c * 4;
#pragma unroll
        for (int j = 0; j < 16; ++j) SLOADC(tw[j], lb, j * 256);

        if (t >= 2) {
#pragma unroll
            for (int r = 0; r < 4; ++r)
                UY[((size_t)brow[r] * T_ + (t - 2)) * H_ + mycol] = yv[r];
        }
        {
            const int tn = (t + 1 < T_) ? (t + 1) : t;
#pragma unroll
            for (int r = 0; r < 4; ++r) {
                const float* ub = UY + ((size_t)brow[r] * T_ + tn) * H_ + mycol;
                ULOAD(uun[r], ub);
            }
        }

        // ==== wait + verify; retry is fence-free (sc0sc1 reads IC truth) ====
        int spin = 0;
        for (;;) {
            asm volatile("s_waitcnt vmcnt(0)" ::: "memory");
            __builtin_amdgcn_sched_barrier(0);
            unsigned mn = 0xFFFFFFFFu;
#pragma unroll
            for (int j = 0; j < 16; ++j) {
                unsigned m01 = tw[j][0] < tw[j][1] ? tw[j][0] : tw[j][1];
                unsigned m23 = tw[j][2] < tw[j][3] ? tw[j][2] : tw[j][3];
                unsigned m = m01 < m23 ? m01 : m23;
                mn = mn < m ? mn : m;
            }
            if (__all((mn >> 16) == tagr)) break;
            if (((++spin) & 7) == 7)
                __builtin_amdgcn_fence(__ATOMIC_ACQUIRE, "agent");  // fallback
            __builtin_amdgcn_s_sleep(1);
#pragma unroll
            for (int j = 0; j < 16; ++j) SLOADC(tw[j], lb, j * 256);
        }

        // ==== LN partial stats of this row ====
        float s1 = 0.f, s2 = 0.f;
#pragma unroll
        for (int j = 0; j < 16; ++j) {
#pragma unroll
            for (int k = 0; k < 4; ++k) {
                const float v = __uint_as_float(tw[j][k] << 16);
                s1 += v;
                s2 = fmaf(v, v, s2);
            }
        }
        s1 += __shfl_xor(s1, 1); s2 += __shfl_xor(s2, 1);
        s1 += __shfl_xor(s1, 2); s2 += __shfl_xor(s2, 2);
        s1 += __shfl_xor(s1, 4); s2 += __shfl_xor(s2, 4);
        s1 += __shfl_xor(s1, 8); s2 += __shfl_xor(s2, 8);
        const float mu_l = s1 * (1.f / (float)H_);
        const float rs_l = rsqrtf(s2 * (1.f / (float)H_) - mu_l * mu_l + 1e-5f);

        // ==== repack to bf16 pairs, share via swizzled LDS ====
#pragma unroll
        for (int j = 0; j < 16; ++j) {
            const unsigned p0 = __builtin_amdgcn_perm(tw[j][1], tw[j][0], 0x05040100u);
            const unsigned p1 = __builtin_amdgcn_perm(tw[j][3], tw[j][2], 0x05040100u);
            const int idx = (j * 32 + c * 2) ^ swzW;
            *(uint2*)&Sl[lrow * 512 + idx] = uint2{p0, p1};
        }
        __syncthreads();   // (B)

        // ==== MFMA from LDS: acc = s_t @ Wslice^T ====
        f32x4 a0 = {0.f, 0.f, 0.f, 0.f}, a1 = a0, a2 = a0, a3 = a0;
#pragma unroll
        for (int kk = 0; kk < 32; kk += 4) {
#pragma unroll
            for (int q = 0; q < 4; ++q) {
                const int ai = ((kk + q) * 16 + rgrp * 4) ^ swzR;
                const uint32x4 aw = *(const uint32x4*)&Sl[c * 512 + ai];
                const bf16x8 af = __builtin_bit_cast(bf16x8, aw);
                const bf16x8 bf = *(const bf16x8*)(Wl +
                    ((size_t)((kk + q) * 4 + rgrp) * 64 + wave * 16 + c) * 8);
                if (q == 0) a0 = __builtin_amdgcn_mfma_f32_16x16x32_bf16(af, bf, a0, 0, 0, 0);
                if (q == 1) a1 = __builtin_amdgcn_mfma_f32_16x16x32_bf16(af, bf, a1, 0, 0, 0);
                if (q == 2) a2 = __builtin_amdgcn_mfma_f32_16x16x32_bf16(af, bf, a2, 0, 0, 0);
                if (q == 3) a3 = __builtin_amdgcn_mfma_f32_16x16x32_bf16(af, bf, a3, 0, 0, 0);
            }
        }
        const f32x4 acc = (a0 + a1) + (a2 + a3);

        // ==== update + publish tagged state (relaxed agent stores) ====
        float sprev[4];
#pragma unroll
        for (int r = 0; r < 4; ++r) {
            sprev[r] = sold[r];
            const float pre = acc[r] + uu[r] + bs_c;
            const float sn  = d_c * sold[r] + od_c * fast_tanh(pre);
            sold[r] = sn;
            __hip_atomic_store(&Sw[(size_t)(rgrp * 4 + r) * 1024 + mycol],
                               (tagw << 16) | f2bf_bits(sn),
                               __ATOMIC_RELAXED, __HIP_MEMORY_SCOPE_AGENT);
        }

        // ==== shadow: stats exchange; yv = y_{t-1} (stored next iter) ====
        __syncthreads();   // (C) MFMA Sl reads done (muS overlays Sl)
        if (c == 0) { muS[lrow] = mu_l; rsS[lrow] = rs_l; }
        __syncthreads();   // (D)
        if (t > 0) {
#pragma unroll
            for (int r = 0; r < 4; ++r) {
                const int R = rgrp * 4 + r;
                yv[r] = (sprev[r] - muS[R]) * rsS[R] * g_c + be_c;
            }
        }
    }

    // ==== epilogue: store y_510 (yv), then y_511 = LN(s_512) ====
    {
#pragma unroll
        for (int r = 0; r < 4; ++r)
            UY[((size_t)brow[r] * T_ + (T_ - 2)) * H_ + mycol] = yv[r];

        const unsigned* Sr = Sg + ((size_t)(T_ % 3) << 14);
        const unsigned tagr = (unsigned)T_;
        uint32x4 tw[16];
        const unsigned* lb = Sr + (size_t)lrow * 1024 + c * 4;
        int spin = 0;
#pragma unroll
        for (int j = 0; j < 16; ++j) SLOADC(tw[j], lb, j * 256);
        for (;;) {
            asm volatile("s_waitcnt vmcnt(0)" ::: "memory");
            __builtin_amdgcn_sched_barrier(0);
            unsigned mn = 0xFFFFFFFFu;
#pragma unroll
            for (int j = 0; j < 16; ++j) {
                unsigned m01 = tw[j][0] < tw[j][1] ? tw[j][0] : tw[j][1];
                unsigned m23 = tw[j][2] < tw[j][3] ? tw[j][2] : tw[j][3];
                unsigned m = m01 < m23 ? m01 : m23;
                mn = mn < m ? mn : m;
            }
            if (__all((mn >> 16) == tagr)) break;
            if (((++spin) & 7) == 7)
                __builtin_amdgcn_fence(__ATOMIC_ACQUIRE, "agent");
            __builtin_amdgcn_s_sleep(1);
#pragma unroll
            for (int j = 0; j < 16; ++j) SLOADC(tw[j], lb, j * 256);
        }
        float s1 = 0.f, s2 = 0.f;
#pragma unroll
        for (int j = 0; j < 16; ++j) {
#pragma unroll
            for (int k = 0; k < 4; ++k) {
                const float v = __uint_as_float(tw[j][k] << 16);
                s1 += v;
                s2 = fmaf(v, v, s2);
            }
        }
        s1 += __shfl_xor(s1, 1); s2 += __shfl_xor(s2, 1);
        s1 += __shfl_xor(s1, 2); s2 += __shfl_xor(s2, 2);
        s1 += __shfl_xor(s1, 4); s2 += __shfl_xor(s2, 4);
        s1 += __shfl_xor(s1, 8); s2 += __shfl_xor(s2, 8);
        const float mu_l = s1 * (1.f / (float)H_);
        const float rs_l = rsqrtf(s2 * (1.f / (float)H_) - mu_l * mu_l + 1e-5f);
        __syncthreads();                      // last yv reads of muS done
        if (c == 0) { muS[lrow] = mu_l; rsS[lrow] = rs_l; }
        __syncthreads();
#pragma unroll
        for (int r = 0; r < 4; ++r) {
            const int R = rgrp * 4 + r;
            UY[((size_t)brow[r] * T_ + (T_ - 1)) * H_ + mycol] =
                (sold[r] - muS[R]) * rsS[R] * g_c + be_c;
        }
    }
}

// ---------------------------------------------------------------------------
extern "C" void kernel_launch(void* const* d_in, const int* in_sizes, int n_in,
                              void* d_out, int out_size, void* d_ws, size_t ws_size,
                              hipStream_t stream) {
    const float* x   = (const float*)d_in[0];
    const float* Win = (const float*)d_in[1];
    const float* bin = (const float*)d_in[2];
    const float* Wst = (const float*)d_in[3];
    const float* bst = (const float*)d_in[4];
    const float* dec = (const float*)d_in[5];
    const float* lng = (const float*)d_in[6];
    const float* lnb = (const float*)d_in[7];
    float* out = (float*)d_out;

    unsigned char* ws = (unsigned char*)d_ws;
    unsigned* Sbuf = (unsigned*)(ws + 4096);     // 4 groups x 3 parities x 64KB

    hipFuncSetAttribute(reinterpret_cast<const void*>(rec_tag2),
                        hipFuncAttributeMaxDynamicSharedMemorySize, 163840);

    hipMemsetAsync(Sbuf, 0, 4u * 3u * 16u * 1024u * 4u, stream);  // tag0 = s_0
    u_gemm<<<dim3(8, 256), 256, 0, stream>>>(x, Win, bin, out);
    rec_tag2<<<64, 256, 163840, stream>>>(Wst, out, bst, dec, lng, lnb, Sbuf);
}